// Round 15
// baseline (118.953 us; speedup 1.0000x reference)
//
#include <hip/hip_runtime.h>

#define NN 50000
#define NE 800000
#define ET (NE + NN)
#define SLOPE 0.2f
#define GEPS 1e-16f
#define NBUK 196     // ceil(NN/256) dst-buckets of 256 nodes
#define BCAP 8192    // per-bucket edge capacity (avg 4080, max ~4400)
#define CCHUNK 2048  // edges per partition block
#define NPB ((NE + CCHUNK - 1) / CCHUNK)  // 391 partition blocks
#define RBKS ((NN + 63) / 64)             // 782 gemm row-blocks

typedef _Float16 f16;
typedef f16 f16x4 __attribute__((ext_vector_type(4)));
typedef f16 f16x8 __attribute__((ext_vector_type(8)));
typedef float f32x4 __attribute__((ext_vector_type(4)));

// ---- shared GEMM body: H(f16) = A(N x 128) @ W(128 x NC) + att dots ----
// W staged DIRECTLY from f32 source (L2-resident, 64KB), transposed to
// [col][K] f16 in LDS during staging. Same rn conversion as before.
template <int NC, bool AF32>
__device__ __forceinline__ void gemm_body(
    f16* __restrict__ Ah, f16* __restrict__ Wh, const void* __restrict__ Av,
    const float* __restrict__ W, const float* __restrict__ atts,
    const float* __restrict__ attd, f16* __restrict__ Hh,
    float* __restrict__ a_s, float* __restrict__ a_d, int N, int bx, int by,
    int tid) {
  constexpr int K = 128, BM = 64, KP = K + 8;
  const int row0 = bx * BM;
  const int col0 = by * 64;
  if (AF32) {
    const float* A = (const float*)Av;
#pragma unroll
    for (int j = 0; j < 8; ++j) {
      int idx = j * 256 + tid;
      int r = idx >> 5, col = (idx & 31) << 2;
      int gr = row0 + r;
      float4 v = make_float4(0.f, 0.f, 0.f, 0.f);
      if (gr < N) v = *(const float4*)((const float*)A + (size_t)gr * K + col);
      f16x4 hv = {(f16)v.x, (f16)v.y, (f16)v.z, (f16)v.w};
      *(f16x4*)&Ah[r * KP + col] = hv;
    }
  } else {
    const f16* A = (const f16*)Av;
#pragma unroll
    for (int j = 0; j < 4; ++j) {
      int idx = j * 256 + tid;
      int r = idx >> 4, col = (idx & 15) << 3;
      int gr = row0 + r;
      f16x8 v = {};
      if (gr < N) v = *(const f16x8*)(A + (size_t)gr * K + col);
      *(f16x8*)&Ah[r * KP + col] = v;
    }
  }
  // stage W panel: read W[k][col0+c] (f32, coalesced), write Wh[c*KP+k] f16
#pragma unroll
  for (int j = 0; j < 8; ++j) {
    int idx = j * 256 + tid;            // 2048 float4s
    int k = idx >> 4, c4 = (idx & 15) << 2;
    float4 v = *(const float4*)(W + (size_t)k * NC + col0 + c4);
    Wh[(c4 + 0) * KP + k] = (f16)v.x;
    Wh[(c4 + 1) * KP + k] = (f16)v.y;
    Wh[(c4 + 2) * KP + k] = (f16)v.z;
    Wh[(c4 + 3) * KP + k] = (f16)v.w;
  }
  __syncthreads();
  const int lane = tid & 63;
  const int w = tid >> 6;
  const int lr = lane & 15;
  const int lk = (lane >> 4) << 3;
  f32x4 acc[4];
#pragma unroll
  for (int cf = 0; cf < 4; ++cf) acc[cf] = (f32x4){0.f, 0.f, 0.f, 0.f};
  const f16* arow = Ah + (w * 16 + lr) * KP + lk;
  const f16* bhrow = Wh + lr * KP + lk;
#pragma unroll
  for (int ks = 0; ks < 4; ++ks) {
    int k0 = ks * 32;
    f16x8 af = *(const f16x8*)(arow + k0);
#pragma unroll
    for (int cf = 0; cf < 4; ++cf) {
      f16x8 bh = *(const f16x8*)(bhrow + cf * 16 * KP + k0);
      acc[cf] = __builtin_amdgcn_mfma_f32_16x16x32_f16(af, bh, acc[cf], 0, 0, 0);
    }
  }
  const int rbase = row0 + w * 16 + ((lane >> 4) << 2);
#pragma unroll
  for (int cf = 0; cf < 4; ++cf) {
    int col = col0 + cf * 16 + lr;
#pragma unroll
    for (int r4 = 0; r4 < 4; ++r4) {
      int gr = rbase + r4;
      if (gr < N) Hh[(size_t)gr * NC + col] = (f16)acc[cf][r4];
    }
  }
  float asc[4], adc[4];
#pragma unroll
  for (int cf = 0; cf < 4; ++cf) {
    asc[cf] = atts[col0 + cf * 16 + lr];
    adc[cf] = attd[col0 + cf * 16 + lr];
  }
  if (NC == 128) {
#pragma unroll
    for (int m = 0; m < 2; ++m) {
#pragma unroll
      for (int r4 = 0; r4 < 4; ++r4) {
        float sp = acc[2 * m][r4] * asc[2 * m] + acc[2 * m + 1][r4] * asc[2 * m + 1];
        float dp = acc[2 * m][r4] * adc[2 * m] + acc[2 * m + 1][r4] * adc[2 * m + 1];
        sp += __shfl_xor(sp, 1); sp += __shfl_xor(sp, 2);
        sp += __shfl_xor(sp, 4); sp += __shfl_xor(sp, 8);
        dp += __shfl_xor(dp, 1); dp += __shfl_xor(dp, 2);
        dp += __shfl_xor(dp, 4); dp += __shfl_xor(dp, 8);
        int gr = rbase + r4;
        if (lr == 0 && gr < N) {
          int hd = by * 2 + m;
          a_s[gr * 4 + hd] = sp;
          a_d[gr * 4 + hd] = dp;
        }
      }
    }
  } else {
#pragma unroll
    for (int r4 = 0; r4 < 4; ++r4) {
      float sp = acc[0][r4] * asc[0] + acc[1][r4] * asc[1] +
                 acc[2][r4] * asc[2] + acc[3][r4] * asc[3];
      float dp = acc[0][r4] * adc[0] + acc[1][r4] * adc[1] +
                 acc[2][r4] * adc[2] + acc[3][r4] * adc[3];
      sp += __shfl_xor(sp, 1); sp += __shfl_xor(sp, 2);
      sp += __shfl_xor(sp, 4); sp += __shfl_xor(sp, 8);
      dp += __shfl_xor(dp, 1); dp += __shfl_xor(dp, 2);
      dp += __shfl_xor(dp, 4); dp += __shfl_xor(dp, 8);
      int gr = rbase + r4;
      if (lr == 0 && gr < N) {
        a_s[gr] = sp;
        a_d[gr] = dp;
      }
    }
  }
}

// ---- fused: edge partition (blocks 0..NPB-1) || GEMM1+att (rest) ----
// bcursor holds RELATIVE counts (memset 0); position = b*BCAP + ofs + intra.
__global__ __launch_bounds__(256) void fused1_kernel(
    const int* __restrict__ src, const int* __restrict__ dst,
    int* __restrict__ bcursor, unsigned int* __restrict__ ebuf,
    const float* __restrict__ x, const float* __restrict__ W1,
    const float* __restrict__ atts, const float* __restrict__ attd,
    f16* __restrict__ Hh, float* __restrict__ a_s, float* __restrict__ a_d,
    int N) {
  constexpr int KP = 136;
  __shared__ __align__(16) char smem[2 * 64 * KP * sizeof(f16)];
  int t = threadIdx.x;
  if (blockIdx.x < NPB) {
    int* cnt = (int*)smem;
    int* ofs = cnt + NBUK;
    int* lcur = ofs + NBUK;
    for (int i = t; i < NBUK; i += 256) {
      cnt[i] = 0;
      lcur[i] = 0;
    }
    __syncthreads();
    int base = blockIdx.x * CCHUNK;
    int nend = min(base + CCHUNK, NE);
    for (int i = base + t; i < nend; i += 256) atomicAdd(&cnt[dst[i] >> 8], 1);
    __syncthreads();
    for (int i = t; i < NBUK; i += 256)
      if (cnt[i] > 0) ofs[i] = atomicAdd(&bcursor[i], cnt[i]);
    __syncthreads();
    for (int i = base + t; i < nend; i += 256) {
      int d = dst[i];
      int s = src[i];
      int b = d >> 8;
      int p = b * BCAP + ofs[b] + atomicAdd(&lcur[b], 1);
      ebuf[p] = ((unsigned)(d & 255) << 16) | (unsigned)s;
    }
  } else {
    int gb = blockIdx.x - NPB;
    int bx = (gb >= RBKS) ? gb - RBKS : gb;
    int by = (gb >= RBKS) ? 1 : 0;
    f16* Ah = (f16*)smem;
    f16* Wh = Ah + 64 * KP;
    gemm_body<128, true>(Ah, Wh, x, W1, atts, attd, Hh, a_s, a_d, N, bx, by, t);
  }
}

// ---- standalone GEMM2 ----
template <int NC, bool AF32>
__global__ __launch_bounds__(256) void mfma_gemm_kernel(
    const void* __restrict__ Av, const float* __restrict__ W,
    const float* __restrict__ atts, const float* __restrict__ attd,
    f16* __restrict__ Hh, float* __restrict__ a_s, float* __restrict__ a_d,
    int N) {
  constexpr int KP = 136;
  __shared__ f16 Ah[64 * KP];
  __shared__ f16 Wh[64 * KP];
  gemm_body<NC, AF32>(Ah, Wh, Av, W, atts, attd, Hh, a_s, a_d, N,
                      blockIdx.x, blockIdx.y, threadIdx.x);
}

// ---- per-bucket CSR build with integrated bucket-base scan ----
__global__ __launch_bounds__(256) void bcsr_kernel(
    const unsigned int* __restrict__ ebuf, const int* __restrict__ bcursor,
    int* __restrict__ rowptr, unsigned short* __restrict__ csr) {
  __shared__ int sc[256];
  __shared__ int deg[256];
  __shared__ int lcur[256];
  int b = blockIdx.x;
  int t = threadIdx.x;
  int nodes_t = (t < NBUK) ? min(256, NN - t * 256) : 0;
  int v = (t < NBUK) ? (bcursor[t] + nodes_t) : 0;  // bcursor = relative count
  sc[t] = v;
  __syncthreads();
  for (int off = 1; off < 256; off <<= 1) {
    int u = (t >= off) ? sc[t - off] : 0;
    __syncthreads();
    sc[t] += u;
    __syncthreads();
  }
  int cb = (b > 0) ? sc[b - 1] : 0;
  if (b == NBUK - 1 && t == 0) rowptr[NN] = ET;
  int ebase = b * BCAP;
  int count = bcursor[b];
  int n0 = b * 256;
  int nodes = min(256, NN - n0);
  deg[t] = 0;
  __syncthreads();
  for (int i = t; i < count; i += 256) atomicAdd(&deg[ebuf[ebase + i] >> 16], 1);
  __syncthreads();
  int myv = (t < nodes) ? (deg[t] + 1) : 0;  // +1 self-loop
  __syncthreads();
  deg[t] = myv;
  __syncthreads();
  for (int off = 1; off < 256; off <<= 1) {
    int u = (t >= off) ? deg[t - off] : 0;
    __syncthreads();
    deg[t] += u;
    __syncthreads();
  }
  if (t < nodes) {
    int excl = cb + deg[t] - myv;
    rowptr[n0 + t] = excl;
    csr[excl] = (unsigned short)(n0 + t);  // self-loop in slot 0
    lcur[t] = excl + 1;
  }
  __syncthreads();
  for (int i = t; i < count; i += 256) {
    unsigned e = ebuf[ebase + i];
    int p = atomicAdd(&lcur[e >> 16], 1);
    csr[p] = (unsigned short)(e & 0xFFFFu);
  }
}

// ---- layer-1 aggregation: chunked slots, batched up-front gathers ----
__global__ __launch_bounds__(256) void gat1_kernel(
    const int* __restrict__ rowptr, const unsigned short* __restrict__ csr_src,
    const f16* __restrict__ h1, const float* __restrict__ as1,
    const float* __restrict__ ad1, const float* __restrict__ b1,
    f16* __restrict__ out1, int N) {
  int n = (blockIdx.x * 256 + threadIdx.x) >> 6;
  int l = threadIdx.x & 63;
  if (n >= N) return;
  int start = rowptr[n], end = rowptr[n + 1];
  int deg = end - start;
  int c = l & 15, q = l >> 4;
  int hB = c >> 2;
  float ad_b = ad1[n * 4 + hB];
  int chunk = (deg + 3) >> 2;
  int e0 = start + q * chunk;
  int ee = min(e0 + chunk, end);
  float acc[8] = {0.f, 0.f, 0.f, 0.f, 0.f, 0.f, 0.f, 0.f};
  float z = 0.f;
  {  // batch 1: edges e0..e0+3
    int sv[4];
#pragma unroll
    for (int k = 0; k < 4; ++k) {
      int ek = e0 + k;
      sv[k] = csr_src[ek < ee ? ek : start];
    }
    float av[4];
    f16x8 gv[4];
#pragma unroll
    for (int k = 0; k < 4; ++k) {
      av[k] = as1[sv[k] * 4 + hB];
      gv[k] = *(const f16x8*)(h1 + (size_t)sv[k] * 128 + 8 * c);
    }
#pragma unroll
    for (int k = 0; k < 4; ++k) {
      float a = av[k] + ad_b;
      a = (a > 0.f) ? a : SLOPE * a;
      float w = (e0 + k < ee) ? __expf(a) : 0.f;
      z += w;
#pragma unroll
      for (int j = 0; j < 8; ++j) acc[j] += w * (float)gv[k][j];
    }
  }
  if (chunk > 4) {  // wave-uniform: deg 17..24 covered by 2 extra edges
    int sv[2];
#pragma unroll
    for (int k = 0; k < 2; ++k) {
      int ek = e0 + 4 + k;
      sv[k] = csr_src[ek < ee ? ek : start];
    }
    float av[2];
    f16x8 gv[2];
#pragma unroll
    for (int k = 0; k < 2; ++k) {
      av[k] = as1[sv[k] * 4 + hB];
      gv[k] = *(const f16x8*)(h1 + (size_t)sv[k] * 128 + 8 * c);
    }
#pragma unroll
    for (int k = 0; k < 2; ++k) {
      float a = av[k] + ad_b;
      a = (a > 0.f) ? a : SLOPE * a;
      float w = (e0 + 4 + k < ee) ? __expf(a) : 0.f;
      z += w;
#pragma unroll
      for (int j = 0; j < 8; ++j) acc[j] += w * (float)gv[k][j];
    }
  }
  if (chunk > 6) {  // deg 25..32
    int sv[2];
#pragma unroll
    for (int k = 0; k < 2; ++k) {
      int ek = e0 + 6 + k;
      sv[k] = csr_src[ek < ee ? ek : start];
    }
    float av[2];
    f16x8 gv[2];
#pragma unroll
    for (int k = 0; k < 2; ++k) {
      av[k] = as1[sv[k] * 4 + hB];
      gv[k] = *(const f16x8*)(h1 + (size_t)sv[k] * 128 + 8 * c);
    }
#pragma unroll
    for (int k = 0; k < 2; ++k) {
      float a = av[k] + ad_b;
      a = (a > 0.f) ? a : SLOPE * a;
      float w = (e0 + 6 + k < ee) ? __expf(a) : 0.f;
      z += w;
#pragma unroll
      for (int j = 0; j < 8; ++j) acc[j] += w * (float)gv[k][j];
    }
  }
  for (int e = e0 + 8; e < ee; ++e) {  // rare: deg > 32
    int s = csr_src[e];
    float a = as1[s * 4 + hB] + ad_b;
    a = (a > 0.f) ? a : SLOPE * a;
    float w = __expf(a);
    f16x8 g = *(const f16x8*)(h1 + (size_t)s * 128 + 8 * c);
#pragma unroll
    for (int j = 0; j < 8; ++j) acc[j] += w * (float)g[j];
    z += w;
  }
#pragma unroll
  for (int j = 0; j < 8; ++j) {
    acc[j] += __shfl_xor(acc[j], 16);
    acc[j] += __shfl_xor(acc[j], 32);
  }
  z += __shfl_xor(z, 16);
  z += __shfl_xor(z, 32);
  if (q == 0) {
    float inv = 1.f / (z + GEPS);
    float4 bb0 = *(const float4*)(b1 + 8 * c);
    float4 bb1 = *(const float4*)(b1 + 8 * c + 4);
    f16x8 o;
    o[0] = (f16)fmaxf(acc[0] * inv + bb0.x, 0.f);
    o[1] = (f16)fmaxf(acc[1] * inv + bb0.y, 0.f);
    o[2] = (f16)fmaxf(acc[2] * inv + bb0.z, 0.f);
    o[3] = (f16)fmaxf(acc[3] * inv + bb0.w, 0.f);
    o[4] = (f16)fmaxf(acc[4] * inv + bb1.x, 0.f);
    o[5] = (f16)fmaxf(acc[5] * inv + bb1.y, 0.f);
    o[6] = (f16)fmaxf(acc[6] * inv + bb1.z, 0.f);
    o[7] = (f16)fmaxf(acc[7] * inv + bb1.w, 0.f);
    *(f16x8*)(out1 + (size_t)n * 128 + 8 * c) = o;
  }
}

// ---- layer-2 aggregation: chunked slots, 8 slots x 8 lanes ----
__global__ __launch_bounds__(256) void gat2_kernel(
    const int* __restrict__ rowptr, const unsigned short* __restrict__ csr_src,
    const f16* __restrict__ h2, const float* __restrict__ as2,
    const float* __restrict__ ad2, const float* __restrict__ b2,
    float* __restrict__ out, int N) {
  int n = (blockIdx.x * 256 + threadIdx.x) >> 6;
  int l = threadIdx.x & 63;
  if (n >= N) return;
  int start = rowptr[n], end = rowptr[n + 1];
  int deg = end - start;
  int c = l & 7, q = l >> 3;
  float ad = ad2[n];
  int chunk = (deg + 7) >> 3;
  int e0 = start + q * chunk;
  int ee = min(e0 + chunk, end);
  float acc[8] = {0.f, 0.f, 0.f, 0.f, 0.f, 0.f, 0.f, 0.f};
  float z = 0.f;
  {  // batch: edges e0..e0+3 (covers deg <= 32)
    int sv[4];
#pragma unroll
    for (int k = 0; k < 4; ++k) {
      int ek = e0 + k;
      sv[k] = csr_src[ek < ee ? ek : start];
    }
    float av[4];
    f16x8 gv[4];
#pragma unroll
    for (int k = 0; k < 4; ++k) {
      av[k] = as2[sv[k]];
      gv[k] = *(const f16x8*)(h2 + (size_t)sv[k] * 64 + 8 * c);
    }
#pragma unroll
    for (int k = 0; k < 4; ++k) {
      float a = av[k] + ad;
      a = (a > 0.f) ? a : SLOPE * a;
      float w = (e0 + k < ee) ? __expf(a) : 0.f;
      z += w;
#pragma unroll
      for (int j = 0; j < 8; ++j) acc[j] += w * (float)gv[k][j];
    }
  }
  for (int e = e0 + 4; e < ee; ++e) {  // rare: deg > 32
    int s = csr_src[e];
    float a = as2[s] + ad;
    a = (a > 0.f) ? a : SLOPE * a;
    float w = __expf(a);
    f16x8 g = *(const f16x8*)(h2 + (size_t)s * 64 + 8 * c);
#pragma unroll
    for (int j = 0; j < 8; ++j) acc[j] += w * (float)g[j];
    z += w;
  }
#pragma unroll
  for (int j = 0; j < 8; ++j) {
    acc[j] += __shfl_xor(acc[j], 8);
    acc[j] += __shfl_xor(acc[j], 16);
    acc[j] += __shfl_xor(acc[j], 32);
  }
  z += __shfl_xor(z, 8);
  z += __shfl_xor(z, 16);
  z += __shfl_xor(z, 32);
  if (q == 0) {
    float inv = 1.f / (z + GEPS);
    float4 bb0 = *(const float4*)(b2 + 8 * c);
    float4 bb1 = *(const float4*)(b2 + 8 * c + 4);
    float4 o0, o1;
    o0.x = fmaxf(acc[0] * inv + bb0.x, 0.f);
    o0.y = fmaxf(acc[1] * inv + bb0.y, 0.f);
    o0.z = fmaxf(acc[2] * inv + bb0.z, 0.f);
    o0.w = fmaxf(acc[3] * inv + bb0.w, 0.f);
    o1.x = fmaxf(acc[4] * inv + bb1.x, 0.f);
    o1.y = fmaxf(acc[5] * inv + bb1.y, 0.f);
    o1.z = fmaxf(acc[6] * inv + bb1.z, 0.f);
    o1.w = fmaxf(acc[7] * inv + bb1.w, 0.f);
    *(float4*)(out + (size_t)n * 64 + 8 * c) = o0;
    *(float4*)(out + (size_t)n * 64 + 8 * c + 4) = o1;
  }
}

extern "C" void kernel_launch(void* const* d_in, const int* in_sizes, int n_in,
                              void* d_out, int out_size, void* d_ws, size_t ws_size,
                              hipStream_t stream) {
  const float* x = (const float*)d_in[0];
  const int* ei = (const int*)d_in[1];
  const float* W1 = (const float*)d_in[2];
  const float* att_s1 = (const float*)d_in[3];
  const float* att_d1 = (const float*)d_in[4];
  const float* b1 = (const float*)d_in[5];
  const float* W2 = (const float*)d_in[6];
  const float* att_s2 = (const float*)d_in[7];
  const float* att_d2 = (const float*)d_in[8];
  const float* b2 = (const float*)d_in[9];
  float* out = (float*)d_out;

  char* ws = (char*)d_ws;
  size_t off = 0;
  auto alloc = [&](size_t bytes) {
    off = (off + 255) & ~(size_t)255;
    void* p = ws + off;
    off += bytes;
    return p;
  };
  int* bcursor = (int*)alloc(NBUK * sizeof(int));
  unsigned int* ebuf = (unsigned int*)alloc((size_t)NBUK * BCAP * sizeof(unsigned int));
  int* rowptr = (int*)alloc((NN + 1) * sizeof(int));
  unsigned short* csr_src = (unsigned short*)alloc((size_t)ET * sizeof(unsigned short));
  f16* h1 = (f16*)alloc((size_t)NN * 128 * sizeof(f16));
  float* as1 = (float*)alloc((size_t)NN * 4 * sizeof(float));
  float* ad1 = (float*)alloc((size_t)NN * 4 * sizeof(float));
  f16* out1h = (f16*)alloc((size_t)NN * 128 * sizeof(f16));
  f16* hh2 = h1;  // layer-2 features reuse h1 (dead after gat1)
  float* as2 = as1;
  float* ad2 = ad1;

  const int* src = ei;
  const int* dst = ei + NE;

  hipMemsetAsync(bcursor, 0, NBUK * sizeof(int), stream);
  hipLaunchKernelGGL(fused1_kernel, dim3(NPB + 2 * RBKS), dim3(256), 0, stream, src,
                     dst, bcursor, ebuf, x, W1, att_s1, att_d1, h1, as1, ad1, NN);
  hipLaunchKernelGGL(bcsr_kernel, dim3(NBUK), dim3(256), 0, stream, ebuf, bcursor,
                     rowptr, csr_src);
  hipLaunchKernelGGL(gat1_kernel, dim3((NN + 3) / 4), dim3(256), 0, stream, rowptr,
                     csr_src, h1, as1, ad1, b1, out1h, NN);
  hipLaunchKernelGGL((mfma_gemm_kernel<64, false>), dim3(RBKS, 1), dim3(256), 0,
                     stream, out1h, W2, att_s2, att_d2, hh2, as2, ad2, NN);
  hipLaunchKernelGGL(gat2_kernel, dim3((NN + 3) / 4), dim3(256), 0, stream, rowptr,
                     csr_src, hh2, as2, ad2, b2, out, NN);
}

// Round 16
// 112.224 us; speedup vs baseline: 1.0600x; 1.0600x over previous
//
#include <hip/hip_runtime.h>

#define NN 50000
#define NE 800000
#define ET (NE + NN)
#define SLOPE 0.2f
#define GEPS 1e-16f
#define NBUK 196     // ceil(NN/256) dst-buckets of 256 nodes
#define BCAP 8192    // per-bucket edge capacity (avg 4080, max ~4400)
#define CCHUNK 2048  // edges per partition block
#define NPB ((NE + CCHUNK - 1) / CCHUNK)  // 391 partition blocks
#define RBKS ((NN + 63) / 64)             // 782 gemm row-blocks

typedef _Float16 f16;
typedef f16 f16x4 __attribute__((ext_vector_type(4)));
typedef f16 f16x8 __attribute__((ext_vector_type(8)));
typedef float f32x4 __attribute__((ext_vector_type(4)));

// ---- W prep (f16, transposed to [col][K]) + bucket cursor init ----
// wt: [0]=W1(128x128) [16384]=W2(64x128)
__global__ __launch_bounds__(256) void wprep_kernel(const float* __restrict__ W1,
                                                    const float* __restrict__ W2,
                                                    f16* __restrict__ wt,
                                                    int* __restrict__ bcursor) {
  int idx = blockIdx.x * 256 + threadIdx.x;
  if (idx < 16384) {
    int c = idx >> 7, k = idx & 127;
    wt[c * 128 + k] = (f16)W1[k * 128 + c];
  } else if (idx < 24576) {
    int i2 = idx - 16384;
    int c = i2 >> 7, k = i2 & 127;
    wt[16384 + c * 128 + k] = (f16)W2[k * 64 + c];
  } else if (idx - 24576 < NBUK) {
    int b = idx - 24576;
    bcursor[b] = b * BCAP;
  }
}

// ---- shared GEMM body: H(f16) = A(N x 128) @ W(128 x NC) + att dots ----
template <int NC, bool AF32>
__device__ __forceinline__ void gemm_body(
    f16* __restrict__ Ah, f16* __restrict__ Wh, const void* __restrict__ Av,
    const f16* __restrict__ whi, const float* __restrict__ atts,
    const float* __restrict__ attd, f16* __restrict__ Hh,
    float* __restrict__ a_s, float* __restrict__ a_d, int N, int bx, int by,
    int tid) {
  constexpr int K = 128, BM = 64, KP = K + 8;
  const int row0 = bx * BM;
  const int col0 = by * 64;
  if (AF32) {
    const float* A = (const float*)Av;
#pragma unroll
    for (int j = 0; j < 8; ++j) {
      int idx = j * 256 + tid;
      int r = idx >> 5, col = (idx & 31) << 2;
      int gr = row0 + r;
      float4 v = make_float4(0.f, 0.f, 0.f, 0.f);
      if (gr < N) v = *(const float4*)((const float*)A + (size_t)gr * K + col);
      f16x4 hv = {(f16)v.x, (f16)v.y, (f16)v.z, (f16)v.w};
      *(f16x4*)&Ah[r * KP + col] = hv;
    }
  } else {
    const f16* A = (const f16*)Av;
#pragma unroll
    for (int j = 0; j < 4; ++j) {
      int idx = j * 256 + tid;
      int r = idx >> 4, col = (idx & 15) << 3;
      int gr = row0 + r;
      f16x8 v = {};
      if (gr < N) v = *(const f16x8*)(A + (size_t)gr * K + col);
      *(f16x8*)&Ah[r * KP + col] = v;
    }
  }
#pragma unroll
  for (int j = 0; j < 4; ++j) {
    int idx = j * 256 + tid;
    int r = idx >> 4, col = (idx & 15) << 3;
    *(f16x8*)&Wh[r * KP + col] =
        *(const f16x8*)(whi + (size_t)(col0 + r) * K + col);
  }
  __syncthreads();
  const int lane = tid & 63;
  const int w = tid >> 6;
  const int lr = lane & 15;
  const int lk = (lane >> 4) << 3;
  f32x4 acc[4];
#pragma unroll
  for (int cf = 0; cf < 4; ++cf) acc[cf] = (f32x4){0.f, 0.f, 0.f, 0.f};
  const f16* arow = Ah + (w * 16 + lr) * KP + lk;
  const f16* bhrow = Wh + lr * KP + lk;
#pragma unroll
  for (int ks = 0; ks < 4; ++ks) {
    int k0 = ks * 32;
    f16x8 af = *(const f16x8*)(arow + k0);
#pragma unroll
    for (int cf = 0; cf < 4; ++cf) {
      f16x8 bh = *(const f16x8*)(bhrow + cf * 16 * KP + k0);
      acc[cf] = __builtin_amdgcn_mfma_f32_16x16x32_f16(af, bh, acc[cf], 0, 0, 0);
    }
  }
  const int rbase = row0 + w * 16 + ((lane >> 4) << 2);
#pragma unroll
  for (int cf = 0; cf < 4; ++cf) {
    int col = col0 + cf * 16 + lr;
#pragma unroll
    for (int r4 = 0; r4 < 4; ++r4) {
      int gr = rbase + r4;
      if (gr < N) Hh[(size_t)gr * NC + col] = (f16)acc[cf][r4];
    }
  }
  float asc[4], adc[4];
#pragma unroll
  for (int cf = 0; cf < 4; ++cf) {
    asc[cf] = atts[col0 + cf * 16 + lr];
    adc[cf] = attd[col0 + cf * 16 + lr];
  }
  if (NC == 128) {
#pragma unroll
    for (int m = 0; m < 2; ++m) {
#pragma unroll
      for (int r4 = 0; r4 < 4; ++r4) {
        float sp = acc[2 * m][r4] * asc[2 * m] + acc[2 * m + 1][r4] * asc[2 * m + 1];
        float dp = acc[2 * m][r4] * adc[2 * m] + acc[2 * m + 1][r4] * adc[2 * m + 1];
        sp += __shfl_xor(sp, 1); sp += __shfl_xor(sp, 2);
        sp += __shfl_xor(sp, 4); sp += __shfl_xor(sp, 8);
        dp += __shfl_xor(dp, 1); dp += __shfl_xor(dp, 2);
        dp += __shfl_xor(dp, 4); dp += __shfl_xor(dp, 8);
        int gr = rbase + r4;
        if (lr == 0 && gr < N) {
          int hd = by * 2 + m;
          a_s[gr * 4 + hd] = sp;
          a_d[gr * 4 + hd] = dp;
        }
      }
    }
  } else {
#pragma unroll
    for (int r4 = 0; r4 < 4; ++r4) {
      float sp = acc[0][r4] * asc[0] + acc[1][r4] * asc[1] +
                 acc[2][r4] * asc[2] + acc[3][r4] * asc[3];
      float dp = acc[0][r4] * adc[0] + acc[1][r4] * adc[1] +
                 acc[2][r4] * adc[2] + acc[3][r4] * adc[3];
      sp += __shfl_xor(sp, 1); sp += __shfl_xor(sp, 2);
      sp += __shfl_xor(sp, 4); sp += __shfl_xor(sp, 8);
      dp += __shfl_xor(dp, 1); dp += __shfl_xor(dp, 2);
      dp += __shfl_xor(dp, 4); dp += __shfl_xor(dp, 8);
      int gr = rbase + r4;
      if (lr == 0 && gr < N) {
        a_s[gr] = sp;
        a_d[gr] = dp;
      }
    }
  }
}

// ---- fused: edge partition (blocks 0..NPB-1) || GEMM1+att (rest) ----
__global__ __launch_bounds__(256) void fused1_kernel(
    const int* __restrict__ src, const int* __restrict__ dst,
    int* __restrict__ bcursor, unsigned int* __restrict__ ebuf,
    const float* __restrict__ x, const f16* __restrict__ whi,
    const float* __restrict__ atts, const float* __restrict__ attd,
    f16* __restrict__ Hh, float* __restrict__ a_s, float* __restrict__ a_d,
    int N) {
  constexpr int KP = 136;
  __shared__ __align__(16) char smem[2 * 64 * KP * sizeof(f16)];
  int t = threadIdx.x;
  if (blockIdx.x < NPB) {
    int* cnt = (int*)smem;
    int* ofs = cnt + NBUK;
    int* lcur = ofs + NBUK;
    for (int i = t; i < NBUK; i += 256) {
      cnt[i] = 0;
      lcur[i] = 0;
    }
    __syncthreads();
    int base = blockIdx.x * CCHUNK;
    int nend = min(base + CCHUNK, NE);
    for (int i = base + t; i < nend; i += 256) atomicAdd(&cnt[dst[i] >> 8], 1);
    __syncthreads();
    for (int i = t; i < NBUK; i += 256)
      if (cnt[i] > 0) ofs[i] = atomicAdd(&bcursor[i], cnt[i]);
    __syncthreads();
    for (int i = base + t; i < nend; i += 256) {
      int d = dst[i];
      int s = src[i];
      int b = d >> 8;
      int p = ofs[b] + atomicAdd(&lcur[b], 1);
      ebuf[p] = ((unsigned)(d & 255) << 16) | (unsigned)s;
    }
  } else {
    int gb = blockIdx.x - NPB;
    int bx = (gb >= RBKS) ? gb - RBKS : gb;
    int by = (gb >= RBKS) ? 1 : 0;
    f16* Ah = (f16*)smem;
    f16* Wh = Ah + 64 * KP;
    gemm_body<128, true>(Ah, Wh, x, whi, atts, attd, Hh, a_s, a_d, N, bx, by, t);
  }
}

// ---- standalone GEMM2 ----
template <int NC, bool AF32>
__global__ __launch_bounds__(256) void mfma_gemm_kernel(
    const void* __restrict__ Av, const f16* __restrict__ whi,
    const float* __restrict__ atts, const float* __restrict__ attd,
    f16* __restrict__ Hh, float* __restrict__ a_s, float* __restrict__ a_d,
    int N) {
  constexpr int KP = 136;
  __shared__ f16 Ah[64 * KP];
  __shared__ f16 Wh[64 * KP];
  gemm_body<NC, AF32>(Ah, Wh, Av, whi, atts, attd, Hh, a_s, a_d, N,
                      blockIdx.x, blockIdx.y, threadIdx.x);
}

// ---- per-bucket CSR build with integrated bucket-base scan ----
__global__ __launch_bounds__(256) void bcsr_kernel(
    const unsigned int* __restrict__ ebuf, const int* __restrict__ bcursor,
    int* __restrict__ rowptr, unsigned short* __restrict__ csr) {
  __shared__ int sc[256];
  __shared__ int deg[256];
  __shared__ int lcur[256];
  int b = blockIdx.x;
  int t = threadIdx.x;
  int nodes_t = (t < NBUK) ? min(256, NN - t * 256) : 0;
  int v = (t < NBUK) ? (bcursor[t] - t * BCAP + nodes_t) : 0;
  sc[t] = v;
  __syncthreads();
  for (int off = 1; off < 256; off <<= 1) {
    int u = (t >= off) ? sc[t - off] : 0;
    __syncthreads();
    sc[t] += u;
    __syncthreads();
  }
  int cb = (b > 0) ? sc[b - 1] : 0;
  if (b == NBUK - 1 && t == 0) rowptr[NN] = ET;
  int ebase = b * BCAP;
  int count = bcursor[b] - ebase;
  int n0 = b * 256;
  int nodes = min(256, NN - n0);
  deg[t] = 0;
  __syncthreads();
  for (int i = t; i < count; i += 256) atomicAdd(&deg[ebuf[ebase + i] >> 16], 1);
  __syncthreads();
  int myv = (t < nodes) ? (deg[t] + 1) : 0;  // +1 self-loop
  __syncthreads();
  deg[t] = myv;
  __syncthreads();
  for (int off = 1; off < 256; off <<= 1) {
    int u = (t >= off) ? deg[t - off] : 0;
    __syncthreads();
    deg[t] += u;
    __syncthreads();
  }
  if (t < nodes) {
    int excl = cb + deg[t] - myv;
    rowptr[n0 + t] = excl;
    csr[excl] = (unsigned short)(n0 + t);  // self-loop in slot 0
    lcur[t] = excl + 1;
  }
  __syncthreads();
  for (int i = t; i < count; i += 256) {
    unsigned e = ebuf[ebase + i];
    int p = atomicAdd(&lcur[e >> 16], 1);
    csr[p] = (unsigned short)(e & 0xFFFFu);
  }
}

// ---- layer-1 aggregation: chunked slots, batched up-front gathers ----
__global__ __launch_bounds__(256) void gat1_kernel(
    const int* __restrict__ rowptr, const unsigned short* __restrict__ csr_src,
    const f16* __restrict__ h1, const float* __restrict__ as1,
    const float* __restrict__ ad1, const float* __restrict__ b1,
    f16* __restrict__ out1, int N) {
  int n = (blockIdx.x * 256 + threadIdx.x) >> 6;
  int l = threadIdx.x & 63;
  if (n >= N) return;
  int start = rowptr[n], end = rowptr[n + 1];
  int deg = end - start;
  int c = l & 15, q = l >> 4;
  int hB = c >> 2;
  float ad_b = ad1[n * 4 + hB];
  int chunk = (deg + 3) >> 2;
  int e0 = start + q * chunk;
  int ee = min(e0 + chunk, end);
  float acc[8] = {0.f, 0.f, 0.f, 0.f, 0.f, 0.f, 0.f, 0.f};
  float z = 0.f;
  {  // batch 1: edges e0..e0+3
    int sv[4];
#pragma unroll
    for (int k = 0; k < 4; ++k) {
      int ek = e0 + k;
      sv[k] = csr_src[ek < ee ? ek : start];
    }
    float av[4];
    f16x8 gv[4];
#pragma unroll
    for (int k = 0; k < 4; ++k) {
      av[k] = as1[sv[k] * 4 + hB];
      gv[k] = *(const f16x8*)(h1 + (size_t)sv[k] * 128 + 8 * c);
    }
#pragma unroll
    for (int k = 0; k < 4; ++k) {
      float a = av[k] + ad_b;
      a = (a > 0.f) ? a : SLOPE * a;
      float w = (e0 + k < ee) ? __expf(a) : 0.f;
      z += w;
#pragma unroll
      for (int j = 0; j < 8; ++j) acc[j] += w * (float)gv[k][j];
    }
  }
  if (chunk > 4) {  // wave-uniform: deg 17..24
    int sv[2];
#pragma unroll
    for (int k = 0; k < 2; ++k) {
      int ek = e0 + 4 + k;
      sv[k] = csr_src[ek < ee ? ek : start];
    }
    float av[2];
    f16x8 gv[2];
#pragma unroll
    for (int k = 0; k < 2; ++k) {
      av[k] = as1[sv[k] * 4 + hB];
      gv[k] = *(const f16x8*)(h1 + (size_t)sv[k] * 128 + 8 * c);
    }
#pragma unroll
    for (int k = 0; k < 2; ++k) {
      float a = av[k] + ad_b;
      a = (a > 0.f) ? a : SLOPE * a;
      float w = (e0 + 4 + k < ee) ? __expf(a) : 0.f;
      z += w;
#pragma unroll
      for (int j = 0; j < 8; ++j) acc[j] += w * (float)gv[k][j];
    }
  }
  if (chunk > 6) {  // deg 25..32
    int sv[2];
#pragma unroll
    for (int k = 0; k < 2; ++k) {
      int ek = e0 + 6 + k;
      sv[k] = csr_src[ek < ee ? ek : start];
    }
    float av[2];
    f16x8 gv[2];
#pragma unroll
    for (int k = 0; k < 2; ++k) {
      av[k] = as1[sv[k] * 4 + hB];
      gv[k] = *(const f16x8*)(h1 + (size_t)sv[k] * 128 + 8 * c);
    }
#pragma unroll
    for (int k = 0; k < 2; ++k) {
      float a = av[k] + ad_b;
      a = (a > 0.f) ? a : SLOPE * a;
      float w = (e0 + 6 + k < ee) ? __expf(a) : 0.f;
      z += w;
#pragma unroll
      for (int j = 0; j < 8; ++j) acc[j] += w * (float)gv[k][j];
    }
  }
  for (int e = e0 + 8; e < ee; ++e) {  // rare: deg > 32
    int s = csr_src[e];
    float a = as1[s * 4 + hB] + ad_b;
    a = (a > 0.f) ? a : SLOPE * a;
    float w = __expf(a);
    f16x8 g = *(const f16x8*)(h1 + (size_t)s * 128 + 8 * c);
#pragma unroll
    for (int j = 0; j < 8; ++j) acc[j] += w * (float)g[j];
    z += w;
  }
#pragma unroll
  for (int j = 0; j < 8; ++j) {
    acc[j] += __shfl_xor(acc[j], 16);
    acc[j] += __shfl_xor(acc[j], 32);
  }
  z += __shfl_xor(z, 16);
  z += __shfl_xor(z, 32);
  if (q == 0) {
    float inv = 1.f / (z + GEPS);
    float4 bb0 = *(const float4*)(b1 + 8 * c);
    float4 bb1 = *(const float4*)(b1 + 8 * c + 4);
    f16x8 o;
    o[0] = (f16)fmaxf(acc[0] * inv + bb0.x, 0.f);
    o[1] = (f16)fmaxf(acc[1] * inv + bb0.y, 0.f);
    o[2] = (f16)fmaxf(acc[2] * inv + bb0.z, 0.f);
    o[3] = (f16)fmaxf(acc[3] * inv + bb0.w, 0.f);
    o[4] = (f16)fmaxf(acc[4] * inv + bb1.x, 0.f);
    o[5] = (f16)fmaxf(acc[5] * inv + bb1.y, 0.f);
    o[6] = (f16)fmaxf(acc[6] * inv + bb1.z, 0.f);
    o[7] = (f16)fmaxf(acc[7] * inv + bb1.w, 0.f);
    *(f16x8*)(out1 + (size_t)n * 128 + 8 * c) = o;
  }
}

// ---- layer-2 aggregation: chunked slots, 8 slots x 8 lanes ----
__global__ __launch_bounds__(256) void gat2_kernel(
    const int* __restrict__ rowptr, const unsigned short* __restrict__ csr_src,
    const f16* __restrict__ h2, const float* __restrict__ as2,
    const float* __restrict__ ad2, const float* __restrict__ b2,
    float* __restrict__ out, int N) {
  int n = (blockIdx.x * 256 + threadIdx.x) >> 6;
  int l = threadIdx.x & 63;
  if (n >= N) return;
  int start = rowptr[n], end = rowptr[n + 1];
  int deg = end - start;
  int c = l & 7, q = l >> 3;
  float ad = ad2[n];
  int chunk = (deg + 7) >> 3;
  int e0 = start + q * chunk;
  int ee = min(e0 + chunk, end);
  float acc[8] = {0.f, 0.f, 0.f, 0.f, 0.f, 0.f, 0.f, 0.f};
  float z = 0.f;
  {  // batch: edges e0..e0+3 (covers deg <= 32)
    int sv[4];
#pragma unroll
    for (int k = 0; k < 4; ++k) {
      int ek = e0 + k;
      sv[k] = csr_src[ek < ee ? ek : start];
    }
    float av[4];
    f16x8 gv[4];
#pragma unroll
    for (int k = 0; k < 4; ++k) {
      av[k] = as2[sv[k]];
      gv[k] = *(const f16x8*)(h2 + (size_t)sv[k] * 64 + 8 * c);
    }
#pragma unroll
    for (int k = 0; k < 4; ++k) {
      float a = av[k] + ad;
      a = (a > 0.f) ? a : SLOPE * a;
      float w = (e0 + k < ee) ? __expf(a) : 0.f;
      z += w;
#pragma unroll
      for (int j = 0; j < 8; ++j) acc[j] += w * (float)gv[k][j];
    }
  }
  for (int e = e0 + 4; e < ee; ++e) {  // rare: deg > 32
    int s = csr_src[e];
    float a = as2[s] + ad;
    a = (a > 0.f) ? a : SLOPE * a;
    float w = __expf(a);
    f16x8 g = *(const f16x8*)(h2 + (size_t)s * 64 + 8 * c);
#pragma unroll
    for (int j = 0; j < 8; ++j) acc[j] += w * (float)g[j];
    z += w;
  }
#pragma unroll
  for (int j = 0; j < 8; ++j) {
    acc[j] += __shfl_xor(acc[j], 8);
    acc[j] += __shfl_xor(acc[j], 16);
    acc[j] += __shfl_xor(acc[j], 32);
  }
  z += __shfl_xor(z, 8);
  z += __shfl_xor(z, 16);
  z += __shfl_xor(z, 32);
  if (q == 0) {
    float inv = 1.f / (z + GEPS);
    float4 bb0 = *(const float4*)(b2 + 8 * c);
    float4 bb1 = *(const float4*)(b2 + 8 * c + 4);
    float4 o0, o1;
    o0.x = fmaxf(acc[0] * inv + bb0.x, 0.f);
    o0.y = fmaxf(acc[1] * inv + bb0.y, 0.f);
    o0.z = fmaxf(acc[2] * inv + bb0.z, 0.f);
    o0.w = fmaxf(acc[3] * inv + bb0.w, 0.f);
    o1.x = fmaxf(acc[4] * inv + bb1.x, 0.f);
    o1.y = fmaxf(acc[5] * inv + bb1.y, 0.f);
    o1.z = fmaxf(acc[6] * inv + bb1.z, 0.f);
    o1.w = fmaxf(acc[7] * inv + bb1.w, 0.f);
    *(float4*)(out + (size_t)n * 64 + 8 * c) = o0;
    *(float4*)(out + (size_t)n * 64 + 8 * c + 4) = o1;
  }
}

extern "C" void kernel_launch(void* const* d_in, const int* in_sizes, int n_in,
                              void* d_out, int out_size, void* d_ws, size_t ws_size,
                              hipStream_t stream) {
  const float* x = (const float*)d_in[0];
  const int* ei = (const int*)d_in[1];
  const float* W1 = (const float*)d_in[2];
  const float* att_s1 = (const float*)d_in[3];
  const float* att_d1 = (const float*)d_in[4];
  const float* b1 = (const float*)d_in[5];
  const float* W2 = (const float*)d_in[6];
  const float* att_s2 = (const float*)d_in[7];
  const float* att_d2 = (const float*)d_in[8];
  const float* b2 = (const float*)d_in[9];
  float* out = (float*)d_out;

  char* ws = (char*)d_ws;
  size_t off = 0;
  auto alloc = [&](size_t bytes) {
    off = (off + 255) & ~(size_t)255;
    void* p = ws + off;
    off += bytes;
    return p;
  };
  int* bcursor = (int*)alloc(NBUK * sizeof(int));
  unsigned int* ebuf = (unsigned int*)alloc((size_t)NBUK * BCAP * sizeof(unsigned int));
  int* rowptr = (int*)alloc((NN + 1) * sizeof(int));
  unsigned short* csr_src = (unsigned short*)alloc((size_t)ET * sizeof(unsigned short));
  f16* wt = (f16*)alloc(24576 * sizeof(f16));
  f16* h1 = (f16*)alloc((size_t)NN * 128 * sizeof(f16));
  float* as1 = (float*)alloc((size_t)NN * 4 * sizeof(float));
  float* ad1 = (float*)alloc((size_t)NN * 4 * sizeof(float));
  f16* out1h = (f16*)alloc((size_t)NN * 128 * sizeof(f16));
  f16* hh2 = h1;  // layer-2 features reuse h1 (dead after gat1)
  float* as2 = as1;
  float* ad2 = ad1;

  const int* src = ei;
  const int* dst = ei + NE;

  hipLaunchKernelGGL(wprep_kernel, dim3(97), dim3(256), 0, stream, W1, W2, wt,
                     bcursor);
  hipLaunchKernelGGL(fused1_kernel, dim3(NPB + 2 * RBKS), dim3(256), 0, stream, src,
                     dst, bcursor, ebuf, x, wt, att_s1, att_d1, h1, as1, ad1, NN);
  hipLaunchKernelGGL(bcsr_kernel, dim3(NBUK), dim3(256), 0, stream, ebuf, bcursor,
                     rowptr, csr_src);
  hipLaunchKernelGGL(gat1_kernel, dim3((NN + 3) / 4), dim3(256), 0, stream, rowptr,
                     csr_src, h1, as1, ad1, b1, out1h, NN);
  hipLaunchKernelGGL((mfma_gemm_kernel<64, false>), dim3(RBKS, 1), dim3(256), 0,
                     stream, out1h, wt + 16384, att_s2, att_d2, hh2, as2, ad2, NN);
  hipLaunchKernelGGL(gat2_kernel, dim3((NN + 3) / 4), dim3(256), 0, stream, rowptr,
                     csr_src, hh2, as2, ad2, b2, out, NN);
}